// Round 1
// baseline (1019.594 us; speedup 1.0000x reference)
//
#include <hip/hip_runtime.h>
#include <math.h>

#define LSEQ 8192
#define DIN  512
#define NB   8
#define NO   1024

// ---------------- Kernel 1: weight normalization ----------------
// One block (64 threads = 1 wave) per output row o.
__global__ void norm_kernel(const float* __restrict__ W, float* __restrict__ Wn) {
    const int o = blockIdx.x;
    const int lane = threadIdx.x;  // 0..63
    const float* row = W + (size_t)o * DIN;
    float4 v0 = *(const float4*)(row + lane * 4);
    float4 v1 = *(const float4*)(row + 256 + lane * 4);
    float s = v0.x * v0.x + v0.y * v0.y + v0.z * v0.z + v0.w * v0.w
            + v1.x * v1.x + v1.y * v1.y + v1.z * v1.z + v1.w * v1.w;
#pragma unroll
    for (int m = 32; m; m >>= 1) s += __shfl_xor(s, m, 64);
    const float sq = 22.62741699796952f;  // sqrt(512)
    const float scale = 1.0f / ((1e-4f + sqrtf(s) / sq) * sq);
    float* orow = Wn + (size_t)o * DIN;
    v0.x *= scale; v0.y *= scale; v0.z *= scale; v0.w *= scale;
    v1.x *= scale; v1.y *= scale; v1.z *= scale; v1.w *= scale;
    *(float4*)(orow + lane * 4) = v0;
    *(float4*)(orow + 256 + lane * 4) = v1;
}

// ---------------- Kernel 2: fp32 GEMM fb = Wn @ x ----------------
// 128x128 block tile, BK=16, 256 threads, 8x8 per thread. h-half rows are
// routed to d_out (scan is in-place there), g-half rows to workspace.
#define BM 128
#define BN 128
#define BK 16
#define LDA (BM + 4)
#define LDB (BN + 4)

__global__ __launch_bounds__(256, 3)
void gemm_kernel(const float* __restrict__ Wn, const float* __restrict__ x,
                 float* __restrict__ dst_h, float* __restrict__ dst_g,
                 int o_base, int g_compact) {
    __shared__ float As[BK][LDA];  // transposed: As[k][m]
    __shared__ float Bs[BK][LDB];

    const int b   = blockIdx.z;
    const int o0  = o_base + blockIdx.y * BM;   // global W row of tile start
    const int n0  = blockIdx.x * BN;
    const int tid = threadIdx.x;

    const int dir  = o0 >> 9;        // 0 = forward group, 1 = backward group
    const int half = (o0 >> 8) & 1;  // 0 = h rows, 1 = g rows
    const int j0   = o0 & 255;

    const float* Aptr = Wn + (size_t)o0 * DIN;
    const float* Bptr = x + (size_t)b * DIN * LSEQ + n0;

    float* dst;
    size_t bstride;
    int row0;
    if (half == 0) {
        dst = dst_h; bstride = (size_t)512 * LSEQ; row0 = dir * 256 + j0;
    } else {
        dst = dst_g;
        if (g_compact) { bstride = (size_t)256 * LSEQ; row0 = j0; }
        else           { bstride = (size_t)512 * LSEQ; row0 = dir * 256 + j0; }
    }
    float* Cptr = dst + (size_t)b * bstride + (size_t)row0 * LSEQ + n0;

    const int tm = tid >> 4;  // 0..15
    const int tn = tid & 15;  // 0..15

    float acc[8][8] = {};

    for (int kt = 0; kt < DIN; kt += BK) {
#pragma unroll
        for (int i = 0; i < 2; ++i) {
            const int id = tid + i * 256;            // 0..511
            const int ar = id >> 2, ac = (id & 3) * 4;
            float4 av = *(const float4*)(Aptr + (size_t)ar * DIN + kt + ac);
            As[ac + 0][ar] = av.x;
            As[ac + 1][ar] = av.y;
            As[ac + 2][ar] = av.z;
            As[ac + 3][ar] = av.w;
            const int br = id >> 5, bc = (id & 31) * 4;
            float4 bv = *(const float4*)(Bptr + (size_t)(kt + br) * LSEQ + bc);
            *(float4*)(&Bs[br][bc]) = bv;
        }
        __syncthreads();
#pragma unroll
        for (int k = 0; k < BK; ++k) {
            float a[8], bb[8];
            *(float4*)(a)      = *(const float4*)(&As[k][tm * 8]);
            *(float4*)(a + 4)  = *(const float4*)(&As[k][tm * 8 + 4]);
            *(float4*)(bb)     = *(const float4*)(&Bs[k][tn * 8]);
            *(float4*)(bb + 4) = *(const float4*)(&Bs[k][tn * 8 + 4]);
#pragma unroll
            for (int i = 0; i < 8; ++i)
#pragma unroll
                for (int j = 0; j < 8; ++j)
                    acc[i][j] = fmaf(a[i], bb[j], acc[i][j]);
        }
        __syncthreads();
    }

#pragma unroll
    for (int i = 0; i < 8; ++i) {
        float* crow = Cptr + (size_t)(tm * 8 + i) * LSEQ + tn * 8;
        *(float4*)(crow)     = make_float4(acc[i][0], acc[i][1], acc[i][2], acc[i][3]);
        *(float4*)(crow + 4) = make_float4(acc[i][4], acc[i][5], acc[i][6], acc[i][7]);
    }
}

// ---------------- Kernel 3: minGRU scan ----------------
// H_t = a_t * H_{t-1} + c_t * clamp(h_t),  a = 1/sqrt(1+e^{2g}), c = 1/sqrt(1+e^{-2g}).
// One block per (batch, dir, channel); 256 threads x 32 serial elements;
// wave shuffle scan + cross-wave LDS composite. h lives in `out` (in-place).
__global__ __launch_bounds__(256, 4)
void scan_kernel(const float* __restrict__ gbase, size_t g_bstride_f,
                 int g_dirstride_rows, int dir0, float* __restrict__ out) {
    const int j  = blockIdx.x & 255;
    const int dl = blockIdx.x >> 8;
    const int b  = blockIdx.y;
    const int dir = dir0 + dl;

    const float* hrow = out + ((size_t)b * 512 + dir * 256 + j) * LSEQ;
    const float* grow = gbase + (size_t)b * g_bstride_f
                      + (size_t)(dl * g_dirstride_rows + j) * LSEQ;
    float* orow = out + ((size_t)b * 512 + dir * 256 + j) * LSEQ;

    const int t = threadIdx.x;
    const int l0 = dir ? (LSEQ - 32 - t * 32) : (t * 32);

    float av[32], vv[32];  // stored in MEMORY order (index mo)
#pragma unroll
    for (int q = 0; q < 8; ++q) {
        float4 hq = *(const float4*)(hrow + l0 + q * 4);
        float4 gq = *(const float4*)(grow + l0 + q * 4);
        float hs[4] = {hq.x, hq.y, hq.z, hq.w};
        float gs[4] = {gq.x, gq.y, gq.z, gq.w};
#pragma unroll
        for (int s = 0; s < 4; ++s) {
            const int mo = q * 4 + s;
            float g_ = fminf(fmaxf(gs[s], -30.f), 30.f);
            float eg = __expf(g_);
            float a  = rsqrtf(fmaf(eg, eg, 1.f));
            float c  = a * eg;
            float h_ = hs[s];
            float v  = c * copysignf(fmaxf(fabsf(h_), 1e-6f), h_);
            av[mo] = a; vv[mo] = v;
        }
    }

    // local composite over this thread's 32 elements, in SCAN order
    float A = 1.f, B = 0.f;
    if (dir == 0) {
#pragma unroll
        for (int i = 0; i < 32; ++i) { B = fmaf(av[i], B, vv[i]); A *= av[i]; }
    } else {
#pragma unroll
        for (int i = 31; i >= 0; --i) { B = fmaf(av[i], B, vv[i]); A *= av[i]; }
    }

    // inclusive wave scan of affine composites: (A2,B2)o(A1,B1) = (A1*A2, A2*B1+B2)
    const int lane = t & 63;
    const int wid  = t >> 6;
#pragma unroll
    for (int off = 1; off < 64; off <<= 1) {
        float Ap = __shfl_up(A, (unsigned)off, 64);
        float Bp = __shfl_up(B, (unsigned)off, 64);
        if (lane >= off) { B = fmaf(A, Bp, B); A *= Ap; }
    }
    __shared__ float sA[4], sB[4];
    if (lane == 63) { sA[wid] = A; sB[wid] = B; }
    __syncthreads();
    float WB = 0.f;  // H at entry of this wave (exclusive over previous waves), H0=0
    for (int w = 0; w < wid; ++w) { WB = fmaf(sA[w], WB, sB[w]); }
    float eA = __shfl_up(A, 1u, 64);
    float eB = __shfl_up(B, 1u, 64);
    if (lane == 0) { eA = 1.f; eB = 0.f; }
    float H = fmaf(eA, WB, eB);  // H at entry of this thread's chunk

    // final serial pass, write results (reversed packing for dir=1)
    if (dir == 0) {
#pragma unroll
        for (int q = 0; q < 8; ++q) {
            float4 r;
            H = fmaf(av[q * 4 + 0], H, vv[q * 4 + 0]); r.x = H;
            H = fmaf(av[q * 4 + 1], H, vv[q * 4 + 1]); r.y = H;
            H = fmaf(av[q * 4 + 2], H, vv[q * 4 + 2]); r.z = H;
            H = fmaf(av[q * 4 + 3], H, vv[q * 4 + 3]); r.w = H;
            *(float4*)(orow + l0 + q * 4) = r;
        }
    } else {
#pragma unroll
        for (int q = 7; q >= 0; --q) {
            float4 r;
            H = fmaf(av[q * 4 + 3], H, vv[q * 4 + 3]); r.w = H;
            H = fmaf(av[q * 4 + 2], H, vv[q * 4 + 2]); r.z = H;
            H = fmaf(av[q * 4 + 1], H, vv[q * 4 + 1]); r.y = H;
            H = fmaf(av[q * 4 + 0], H, vv[q * 4 + 0]); r.x = H;
            *(float4*)(orow + l0 + q * 4) = r;
        }
    }
}

// ---------------- launch ----------------
extern "C" void kernel_launch(void* const* d_in, const int* in_sizes, int n_in,
                              void* d_out, int out_size, void* d_ws, size_t ws_size,
                              hipStream_t stream) {
    const float* x = (const float*)d_in[0];  // (8, 512, 8192)
    const float* W = (const float*)d_in[1];  // (1024, 512, 1)
    float* out = (float*)d_out;              // (8, 512, 8192)

    float* Wn    = (float*)d_ws;                       // 1024*512 floats = 2 MB
    float* g_buf = (float*)d_ws + (size_t)NO * DIN;    // g-half of fb

    norm_kernel<<<dim3(NO), dim3(64), 0, stream>>>(W, Wn);

    const size_t need_modeB = (size_t)NO * DIN * 4 + (size_t)NB * 512 * LSEQ * 4;  // ~136.3 MB
    if (ws_size >= need_modeB) {
        // Mode B: single GEMM over all 1024 rows; h-halves -> out, g-halves -> ws.
        dim3 gg(LSEQ / BN, NO / BM, NB);  // (64, 8, 8)
        gemm_kernel<<<gg, dim3(256), 0, stream>>>(Wn, x, out, g_buf, 0, 0);
        dim3 gs(512, NB);                 // both dirs in one dispatch
        scan_kernel<<<gs, dim3(256), 0, stream>>>(g_buf, (size_t)512 * LSEQ, 256, 0, out);
    } else {
        // Mode C: per-direction chunks, g buffer reused (needs ~69 MB).
        for (int d = 0; d < 2; ++d) {
            dim3 gg(LSEQ / BN, 512 / BM, NB);  // (64, 4, 8)
            gemm_kernel<<<gg, dim3(256), 0, stream>>>(Wn, x, out, g_buf, d * 512, 1);
            dim3 gs(256, NB);
            scan_kernel<<<gs, dim3(256), 0, stream>>>(g_buf, (size_t)256 * LSEQ, 0, d, out);
        }
    }
}

// Round 2
// 430.873 us; speedup vs baseline: 2.3663x; 2.3663x over previous
//
#include <hip/hip_runtime.h>
#include <math.h>
#include <stdint.h>

#define LSEQ 8192
#define DIN  512
#define NB   8
#define NO   1024

typedef __bf16 bf16x8 __attribute__((ext_vector_type(8)));
typedef float f32x16 __attribute__((ext_vector_type(16)));

__device__ __forceinline__ uint32_t pack_bf16_rne(float lo, float hi) {
    uint32_t ul = __builtin_bit_cast(uint32_t, lo);
    uint32_t uh = __builtin_bit_cast(uint32_t, hi);
    ul += 0x7FFFu + ((ul >> 16) & 1u);
    uh += 0x7FFFu + ((uh >> 16) & 1u);
    return (ul >> 16) | (uh & 0xFFFF0000u);
}

// ---------------- Kernel 1: weight norm -> bf16 ----------------
__global__ void norm_kernel(const float* __restrict__ W, uint32_t* __restrict__ Wnb) {
    const int o = blockIdx.x;
    const int lane = threadIdx.x;  // 0..63
    const float* row = W + (size_t)o * DIN;
    float4 v0 = *(const float4*)(row + lane * 4);
    float4 v1 = *(const float4*)(row + 256 + lane * 4);
    float s = v0.x * v0.x + v0.y * v0.y + v0.z * v0.z + v0.w * v0.w
            + v1.x * v1.x + v1.y * v1.y + v1.z * v1.z + v1.w * v1.w;
#pragma unroll
    for (int m = 32; m; m >>= 1) s += __shfl_xor(s, m, 64);
    const float sq = 22.62741699796952f;  // sqrt(512)
    const float scale = 1.0f / ((1e-4f + sqrtf(s) / sq) * sq);
    uint2 w0, w1;
    w0.x = pack_bf16_rne(v0.x * scale, v0.y * scale);
    w0.y = pack_bf16_rne(v0.z * scale, v0.w * scale);
    w1.x = pack_bf16_rne(v1.x * scale, v1.y * scale);
    w1.y = pack_bf16_rne(v1.z * scale, v1.w * scale);
    *(uint2*)&Wnb[o * 256 + lane * 2] = w0;
    *(uint2*)&Wnb[o * 256 + 128 + lane * 2] = w1;
}

// ---------------- Kernel 2: bf16 MFMA GEMM ----------------
// C[b][o][l] = sum_k Wn[o][k] * x[b][k][l].  128x128 tile, BK=32, 4 waves,
// each wave 64x64 via 2x2 of mfma_f32_32x32x16_bf16.
// LDS A: [m][k] bf16, 16B granules XOR-swizzled: gran(m,q) at m*64 + (q^(m&3))*16.
// LDS B: k2-pair interleaved words: word(k2,l) = (bf16 x[2k2][l]) | (bf16 x[2k2+1][l]<<16),
//        row pitch 132 words (pad 4) -> 2-way (free) frag reads.
__global__ __launch_bounds__(256)
void gemm_kernel(const uint16_t* __restrict__ Wnb, const float* __restrict__ x,
                 float* __restrict__ out, float* __restrict__ g_buf) {
    __shared__ uint32_t sA[2048];      // 8 KB
    __shared__ uint32_t sB[16 * 132];  // 8448 B

    const int tid  = threadIdx.x;
    const int lane = tid & 63;
    const int w    = tid >> 6;
    const int wm   = w & 1, wn = w >> 1;

    const int o0 = blockIdx.x * 128;
    const int l0 = blockIdx.y * 128;
    const int b  = blockIdx.z;

    const float* xb = x + (size_t)b * DIN * LSEQ + l0;

    // A staging: thread covers granules 2*tid, 2*tid+1 (same row, adjacent q)
    const int am = tid >> 1;
    const int aq = (tid & 1) * 2;
    const uint16_t* arow = Wnb + (size_t)(o0 + am) * DIN + aq * 8;
    const uint32_t aw0 = am * 16 + ((aq ^ (am & 3)) * 4);
    const uint32_t aw1 = am * 16 + (((aq + 1) ^ (am & 3)) * 4);

    // B staging: units u = tid, tid+256 ; k2 = u>>5, lq = u&31
    const int k2a = tid >> 5, lqa = tid & 31;
    const int k2b = (tid + 256) >> 5, lqb = tid & 31;

    f32x16 acc[2][2];
#pragma unroll
    for (int i = 0; i < 2; ++i)
#pragma unroll
        for (int j = 0; j < 2; ++j)
#pragma unroll
            for (int r = 0; r < 16; ++r) acc[i][j][r] = 0.f;

    uint4 aR0, aR1;
    float4 bR0, bR1, bR2, bR3;
    {
        aR0 = *(const uint4*)(arow);
        aR1 = *(const uint4*)(arow + 8);
        const float* p0 = xb + (size_t)(2 * k2a) * LSEQ + lqa * 4;
        bR0 = *(const float4*)(p0);
        bR1 = *(const float4*)(p0 + LSEQ);
        const float* p1 = xb + (size_t)(2 * k2b) * LSEQ + lqb * 4;
        bR2 = *(const float4*)(p1);
        bR3 = *(const float4*)(p1 + LSEQ);
    }

#pragma unroll 1
    for (int it = 0; it < 16; ++it) {
        __syncthreads();
        *(uint4*)&sA[aw0] = aR0;
        *(uint4*)&sA[aw1] = aR1;
        {
            uint4 w0, w1;
            w0.x = pack_bf16_rne(bR0.x, bR1.x);
            w0.y = pack_bf16_rne(bR0.y, bR1.y);
            w0.z = pack_bf16_rne(bR0.z, bR1.z);
            w0.w = pack_bf16_rne(bR0.w, bR1.w);
            *(uint4*)&sB[k2a * 132 + lqa * 4] = w0;
            w1.x = pack_bf16_rne(bR2.x, bR3.x);
            w1.y = pack_bf16_rne(bR2.y, bR3.y);
            w1.z = pack_bf16_rne(bR2.z, bR3.z);
            w1.w = pack_bf16_rne(bR2.w, bR3.w);
            *(uint4*)&sB[k2b * 132 + lqb * 4] = w1;
        }
        __syncthreads();
        if (it + 1 < 16) {
            const int kt = (it + 1) * 32;
            aR0 = *(const uint4*)(arow + kt);
            aR1 = *(const uint4*)(arow + kt + 8);
            const float* p0 = xb + (size_t)(kt + 2 * k2a) * LSEQ + lqa * 4;
            bR0 = *(const float4*)(p0);
            bR1 = *(const float4*)(p0 + LSEQ);
            const float* p1 = xb + (size_t)(kt + 2 * k2b) * LSEQ + lqb * 4;
            bR2 = *(const float4*)(p1);
            bR3 = *(const float4*)(p1 + LSEQ);
        }
#pragma unroll
        for (int kh = 0; kh < 2; ++kh) {
            bf16x8 af[2], bfr[2];
#pragma unroll
            for (int ms = 0; ms < 2; ++ms) {
                const int m = wm * 64 + ms * 32 + (lane & 31);
                const int q = kh * 2 + (lane >> 5);
                af[ms] = *(const bf16x8*)&sA[m * 16 + ((q ^ (m & 3)) * 4)];
            }
#pragma unroll
            for (int ns = 0; ns < 2; ++ns) {
                const int col = wn * 64 + ns * 32 + (lane & 31);
                const int rb = kh * 8 + (lane >> 5) * 4;
                uint4 t;
                t.x = sB[(rb + 0) * 132 + col];
                t.y = sB[(rb + 1) * 132 + col];
                t.z = sB[(rb + 2) * 132 + col];
                t.w = sB[(rb + 3) * 132 + col];
                bfr[ns] = __builtin_bit_cast(bf16x8, t);
            }
#pragma unroll
            for (int ms = 0; ms < 2; ++ms)
#pragma unroll
                for (int ns = 0; ns < 2; ++ns)
                    acc[ms][ns] = __builtin_amdgcn_mfma_f32_32x32x16_bf16(
                        af[ms], bfr[ns], acc[ms][ns], 0, 0, 0);
        }
    }

    // epilogue: route h rows -> out, g rows -> g_buf (both 512-row layouts)
    const int sec = o0 >> 8;                       // 0..3
    float* dst = (sec & 1) ? g_buf : out;
    const int row0 = (sec >> 1) * 256 + (o0 & 255);
    float* base = dst + (size_t)b * 512 * LSEQ + l0;
#pragma unroll
    for (int ms = 0; ms < 2; ++ms)
#pragma unroll
        for (int ns = 0; ns < 2; ++ns) {
            const f32x16 a = acc[ms][ns];
            const int rb = row0 + wm * 64 + ms * 32 + 4 * (lane >> 5);
            const int cc = wn * 64 + ns * 32 + (lane & 31);
#pragma unroll
            for (int r = 0; r < 16; ++r) {
                const int row = rb + (r & 3) + 8 * (r >> 2);
                base[(size_t)row * LSEQ + cc] = a[r];
            }
        }
}

// ---------------- Kernel 3: minGRU scan (coalesced via per-wave LDS windows) ----
// H[l] = a[l]*H[l-1] + v[l] (dir 0) or H[l] = a[l]*H[l+1] + v[l] (dir 1).
// a = 1/sqrt(1+e^{2g}), v = c*clamp(h), c = e^g/sqrt(1+e^{2g}).
__global__ __launch_bounds__(256)
void scan_kernel(const float* __restrict__ g_buf, float* __restrict__ out) {
    __shared__ float sbuf[4][2048];
    __shared__ float sAc[4], sBc[4];

    const int r = blockIdx.x;   // 0..511
    const int b = blockIdx.y;
    const int dir = r >> 8;
    const int t = threadIdx.x;
    const int lane = t & 63;
    const int w = t >> 6;

    const size_t rowoff = ((size_t)b * 512 + r) * LSEQ;
    const float* hrow = out + rowoff;
    const float* grow = g_buf + rowoff;
    float* orow = out + rowoff;

    float* sw = sbuf[w];
    const int wbase = w * 2048;

    // ---- stage h (coalesced) -> swizzled LDS -> per-thread chunk regs ----
#pragma unroll
    for (int i = 0; i < 8; ++i) {
        float4 v = *(const float4*)(hrow + wbase + i * 256 + lane * 4);
        const uint32_t g = i * 64 + lane;
        const uint32_t gs = g ^ ((g >> 3) & 7);
        *(float4*)&sw[gs * 4] = v;
    }
    asm volatile("s_waitcnt lgkmcnt(0)" ::: "memory");
    float hv[32];
#pragma unroll
    for (int q = 0; q < 8; ++q) {
        const uint32_t g = lane * 8 + q;
        const uint32_t gs = g ^ ((g >> 3) & 7);
        float4 v = *(const float4*)&sw[gs * 4];
        hv[q * 4 + 0] = v.x; hv[q * 4 + 1] = v.y;
        hv[q * 4 + 2] = v.z; hv[q * 4 + 3] = v.w;
    }
    // ---- stage g, compute a/v ----
#pragma unroll
    for (int i = 0; i < 8; ++i) {
        float4 v = *(const float4*)(grow + wbase + i * 256 + lane * 4);
        const uint32_t g = i * 64 + lane;
        const uint32_t gs = g ^ ((g >> 3) & 7);
        *(float4*)&sw[gs * 4] = v;
    }
    asm volatile("s_waitcnt lgkmcnt(0)" ::: "memory");
    float av[32], vv[32];
#pragma unroll
    for (int q = 0; q < 8; ++q) {
        const uint32_t g = lane * 8 + q;
        const uint32_t gs = g ^ ((g >> 3) & 7);
        float4 gq = *(const float4*)&sw[gs * 4];
        float gsv[4] = {gq.x, gq.y, gq.z, gq.w};
#pragma unroll
        for (int s = 0; s < 4; ++s) {
            const int mo = q * 4 + s;
            float g_ = fminf(fmaxf(gsv[s], -30.f), 30.f);
            float eg = __expf(g_);
            float a  = rsqrtf(fmaf(eg, eg, 1.f));
            float c  = a * eg;
            float h_ = hv[mo];
            av[mo] = a;
            vv[mo] = c * copysignf(fmaxf(fabsf(h_), 1e-6f), h_);
        }
    }

    // ---- local composite (scan order) ----
    float A = 1.f, B = 0.f;
    if (dir == 0) {
#pragma unroll
        for (int i = 0; i < 32; ++i) { B = fmaf(av[i], B, vv[i]); A *= av[i]; }
    } else {
#pragma unroll
        for (int i = 31; i >= 0; --i) { B = fmaf(av[i], B, vv[i]); A *= av[i]; }
    }
    // ---- wave scan (prefix for dir 0, suffix for dir 1) ----
    if (dir == 0) {
#pragma unroll
        for (int off = 1; off < 64; off <<= 1) {
            float Ap = __shfl_up(A, (unsigned)off, 64);
            float Bp = __shfl_up(B, (unsigned)off, 64);
            if (lane >= off) { B = fmaf(A, Bp, B); A *= Ap; }
        }
        if (lane == 63) { sAc[w] = A; sBc[w] = B; }
    } else {
#pragma unroll
        for (int off = 1; off < 64; off <<= 1) {
            float Ap = __shfl_down(A, (unsigned)off, 64);
            float Bp = __shfl_down(B, (unsigned)off, 64);
            if (lane + off < 64) { B = fmaf(A, Bp, B); A *= Ap; }
        }
        if (lane == 0) { sAc[w] = A; sBc[w] = B; }
    }
    __syncthreads();
    float WB = 0.f;
    if (dir == 0) { for (int wv = 0; wv < w; ++wv) WB = fmaf(sAc[wv], WB, sBc[wv]); }
    else          { for (int wv = 3; wv > w; --wv) WB = fmaf(sAc[wv], WB, sBc[wv]); }
    float eA, eB;
    if (dir == 0) {
        eA = __shfl_up(A, 1u, 64); eB = __shfl_up(B, 1u, 64);
        if (lane == 0) { eA = 1.f; eB = 0.f; }
    } else {
        eA = __shfl_down(A, 1u, 64); eB = __shfl_down(B, 1u, 64);
        if (lane == 63) { eA = 1.f; eB = 0.f; }
    }
    float H = fmaf(eA, WB, eB);

    // ---- final serial pass (results into vv, memory order) ----
    if (dir == 0) {
#pragma unroll
        for (int i = 0; i < 32; ++i) { H = fmaf(av[i], H, vv[i]); vv[i] = H; }
    } else {
#pragma unroll
        for (int i = 31; i >= 0; --i) { H = fmaf(av[i], H, vv[i]); vv[i] = H; }
    }

    // ---- write back via LDS, coalesced stores ----
#pragma unroll
    for (int q = 0; q < 8; ++q) {
        const uint32_t g = lane * 8 + q;
        const uint32_t gs = g ^ ((g >> 3) & 7);
        *(float4*)&sw[gs * 4] = make_float4(vv[q * 4], vv[q * 4 + 1], vv[q * 4 + 2], vv[q * 4 + 3]);
    }
    asm volatile("s_waitcnt lgkmcnt(0)" ::: "memory");
#pragma unroll
    for (int i = 0; i < 8; ++i) {
        const uint32_t g = i * 64 + lane;
        const uint32_t gs = g ^ ((g >> 3) & 7);
        float4 v = *(const float4*)&sw[gs * 4];
        *(float4*)(orow + wbase + i * 256 + lane * 4) = v;
    }
}

// ---------------- launch ----------------
extern "C" void kernel_launch(void* const* d_in, const int* in_sizes, int n_in,
                              void* d_out, int out_size, void* d_ws, size_t ws_size,
                              hipStream_t stream) {
    const float* x = (const float*)d_in[0];  // (8, 512, 8192)
    const float* W = (const float*)d_in[1];  // (1024, 512, 1)
    float* out = (float*)d_out;              // (8, 512, 8192)

    uint32_t* Wnb  = (uint32_t*)d_ws;                                   // 1 MB bf16
    float*    g_buf = (float*)((char*)d_ws + (size_t)NO * DIN * 2);     // 134 MB fp32

    norm_kernel<<<dim3(NO), dim3(64), 0, stream>>>(W, Wnb);
    gemm_kernel<<<dim3(8, 64, NB), dim3(256), 0, stream>>>(
        (const uint16_t*)Wnb, x, out, g_buf);
    scan_kernel<<<dim3(512, NB), dim3(256), 0, stream>>>(g_buf, out);
}

// Round 3
// 357.229 us; speedup vs baseline: 2.8542x; 1.2062x over previous
//
#include <hip/hip_runtime.h>
#include <math.h>
#include <stdint.h>

#define LSEQ 8192
#define DIN  512
#define NB   8
#define NO   1024

typedef __bf16 bf16x8 __attribute__((ext_vector_type(8)));
typedef float f32x16 __attribute__((ext_vector_type(16)));

__device__ __forceinline__ uint32_t pack_bf16_rne(float lo, float hi) {
    uint32_t ul = __builtin_bit_cast(uint32_t, lo);
    uint32_t uh = __builtin_bit_cast(uint32_t, hi);
    ul += 0x7FFFu + ((ul >> 16) & 1u);
    uh += 0x7FFFu + ((uh >> 16) & 1u);
    return (ul >> 16) | (uh & 0xFFFF0000u);
}
__device__ __forceinline__ float bf16_lo(uint32_t w) {
    return __builtin_bit_cast(float, w << 16);
}
__device__ __forceinline__ float bf16_hi(uint32_t w) {
    return __builtin_bit_cast(float, w & 0xFFFF0000u);
}

// ---------------- Kernel 1: weight norm -> bf16 ----------------
__global__ void norm_kernel(const float* __restrict__ W, uint32_t* __restrict__ Wnb) {
    const int o = blockIdx.x;
    const int lane = threadIdx.x;  // 0..63
    const float* row = W + (size_t)o * DIN;
    float4 v0 = *(const float4*)(row + lane * 4);
    float4 v1 = *(const float4*)(row + 256 + lane * 4);
    float s = v0.x * v0.x + v0.y * v0.y + v0.z * v0.z + v0.w * v0.w
            + v1.x * v1.x + v1.y * v1.y + v1.z * v1.z + v1.w * v1.w;
#pragma unroll
    for (int m = 32; m; m >>= 1) s += __shfl_xor(s, m, 64);
    const float sq = 22.62741699796952f;  // sqrt(512)
    const float scale = 1.0f / ((1e-4f + sqrtf(s) / sq) * sq);
    uint2 w0, w1;
    w0.x = pack_bf16_rne(v0.x * scale, v0.y * scale);
    w0.y = pack_bf16_rne(v0.z * scale, v0.w * scale);
    w1.x = pack_bf16_rne(v1.x * scale, v1.y * scale);
    w1.y = pack_bf16_rne(v1.z * scale, v1.w * scale);
    *(uint2*)&Wnb[o * 256 + lane * 2] = w0;
    *(uint2*)&Wnb[o * 256 + 128 + lane * 2] = w1;
}

// ---------------- Kernel 2: bf16 MFMA GEMM, o-pair-packed bf16 output ----
// fbp word (b, o2, l) = bf16 fb[b][2*o2][l] | bf16 fb[b][2*o2+1][l] << 16.
// Grid (512, NB): bx -> (xcd = bx&7 owns l-tiles l%8==xcd; o-tiles iterate
// fastest within an XCD so the x-tile is reused 8x from the same L2).
__global__ __launch_bounds__(256)
void gemm_kernel(const uint16_t* __restrict__ Wnb, const float* __restrict__ x,
                 uint32_t* __restrict__ fbp) {
    __shared__ uint32_t sA[2048];      // 8 KB
    __shared__ uint32_t sB[16 * 132];  // 8448 B

    const int tid  = threadIdx.x;
    const int lane = tid & 63;
    const int w    = tid >> 6;
    const int wm   = w & 1, wn = w >> 1;

    const int bx  = blockIdx.x;
    const int xcd = bx & 7;
    const int t   = bx >> 3;
    const int o0  = (t & 7) * 128;
    const int l0  = (xcd + ((t >> 3) << 3)) * 128;
    const int b   = blockIdx.y;

    const float* xb = x + (size_t)b * DIN * LSEQ + l0;

    const int am = tid >> 1;
    const int aq = (tid & 1) * 2;
    const uint16_t* arow = Wnb + (size_t)(o0 + am) * DIN + aq * 8;
    const uint32_t aw0 = am * 16 + ((aq ^ (am & 3)) * 4);
    const uint32_t aw1 = am * 16 + (((aq + 1) ^ (am & 3)) * 4);

    const int k2a = tid >> 5, lqa = tid & 31;
    const int k2b = (tid + 256) >> 5, lqb = tid & 31;

    f32x16 acc[2][2];
#pragma unroll
    for (int i = 0; i < 2; ++i)
#pragma unroll
        for (int j = 0; j < 2; ++j)
#pragma unroll
            for (int r = 0; r < 16; ++r) acc[i][j][r] = 0.f;

    uint4 aR0, aR1;
    float4 bR0, bR1, bR2, bR3;
    {
        aR0 = *(const uint4*)(arow);
        aR1 = *(const uint4*)(arow + 8);
        const float* p0 = xb + (size_t)(2 * k2a) * LSEQ + lqa * 4;
        bR0 = *(const float4*)(p0);
        bR1 = *(const float4*)(p0 + LSEQ);
        const float* p1 = xb + (size_t)(2 * k2b) * LSEQ + lqb * 4;
        bR2 = *(const float4*)(p1);
        bR3 = *(const float4*)(p1 + LSEQ);
    }

#pragma unroll 1
    for (int it = 0; it < 16; ++it) {
        __syncthreads();
        *(uint4*)&sA[aw0] = aR0;
        *(uint4*)&sA[aw1] = aR1;
        {
            uint4 w0, w1;
            w0.x = pack_bf16_rne(bR0.x, bR1.x);
            w0.y = pack_bf16_rne(bR0.y, bR1.y);
            w0.z = pack_bf16_rne(bR0.z, bR1.z);
            w0.w = pack_bf16_rne(bR0.w, bR1.w);
            *(uint4*)&sB[k2a * 132 + lqa * 4] = w0;
            w1.x = pack_bf16_rne(bR2.x, bR3.x);
            w1.y = pack_bf16_rne(bR2.y, bR3.y);
            w1.z = pack_bf16_rne(bR2.z, bR3.z);
            w1.w = pack_bf16_rne(bR2.w, bR3.w);
            *(uint4*)&sB[k2b * 132 + lqb * 4] = w1;
        }
        __syncthreads();
        if (it + 1 < 16) {
            const int kt = (it + 1) * 32;
            aR0 = *(const uint4*)(arow + kt);
            aR1 = *(const uint4*)(arow + kt + 8);
            const float* p0 = xb + (size_t)(kt + 2 * k2a) * LSEQ + lqa * 4;
            bR0 = *(const float4*)(p0);
            bR1 = *(const float4*)(p0 + LSEQ);
            const float* p1 = xb + (size_t)(kt + 2 * k2b) * LSEQ + lqb * 4;
            bR2 = *(const float4*)(p1);
            bR3 = *(const float4*)(p1 + LSEQ);
        }
#pragma unroll
        for (int kh = 0; kh < 2; ++kh) {
            bf16x8 af[2], bfr[2];
#pragma unroll
            for (int ms = 0; ms < 2; ++ms) {
                const int m = wm * 64 + ms * 32 + (lane & 31);
                const int q = kh * 2 + (lane >> 5);
                af[ms] = *(const bf16x8*)&sA[m * 16 + ((q ^ (m & 3)) * 4)];
            }
#pragma unroll
            for (int ns = 0; ns < 2; ++ns) {
                const int col = wn * 64 + ns * 32 + (lane & 31);
                const int rb = kh * 8 + (lane >> 5) * 4;
                uint4 tt;
                tt.x = sB[(rb + 0) * 132 + col];
                tt.y = sB[(rb + 1) * 132 + col];
                tt.z = sB[(rb + 2) * 132 + col];
                tt.w = sB[(rb + 3) * 132 + col];
                bfr[ns] = __builtin_bit_cast(bf16x8, tt);
            }
#pragma unroll
            for (int ms = 0; ms < 2; ++ms)
#pragma unroll
                for (int ns = 0; ns < 2; ++ns)
                    acc[ms][ns] = __builtin_amdgcn_mfma_f32_32x32x16_bf16(
                        af[ms], bfr[ns], acc[ms][ns], 0, 0, 0);
        }
    }

    // epilogue: pack adjacent-o pairs (adjacent acc regs) -> one uint32 word
    uint32_t* fbp_b = fbp + (size_t)b * 512 * LSEQ + l0;
#pragma unroll
    for (int ms = 0; ms < 2; ++ms)
#pragma unroll
        for (int ns = 0; ns < 2; ++ns) {
            const f32x16 a = acc[ms][ns];
            const int rb = o0 + wm * 64 + ms * 32 + 4 * (lane >> 5);  // even
            const int cc = wn * 64 + ns * 32 + (lane & 31);
#pragma unroll
            for (int rp = 0; rp < 8; ++rp) {
                const int r = rp * 2;
                const int row = rb + (r & 3) + 8 * (r >> 2);  // even
                fbp_b[(size_t)(row >> 1) * LSEQ + cc] = pack_bf16_rne(a[r], a[r + 1]);
            }
        }
}

// ---------------- Kernel 3: minGRU scan over o-pair-packed bf16 fb --------
// Block = (b, dir, channel-pair p): channels c0=2p, c1=2p+1. 512 threads,
// each thread 16 l-positions x 2 channels. Coalesced global <-> LDS windows.
__global__ __launch_bounds__(512)
void scan_kernel(const uint32_t* __restrict__ fbp, float* __restrict__ out) {
    __shared__ uint32_t sbuf[8][2048];  // 64 KB: per-wave 1024 h-words + 1024 g-words
    __shared__ float sA0[8], sB0[8], sA1[8], sB1[8];

    const int bx  = blockIdx.x;       // 0..255
    const int b   = blockIdx.y;
    const int dir = bx >> 7;
    const int p   = bx & 127;
    const int o2h = dir * 256 + p;
    const int o2g = dir * 256 + 128 + p;

    const int t    = threadIdx.x;
    const int lane = t & 63;
    const int w    = t >> 6;

    const uint32_t* hwp = fbp + ((size_t)b * 512 + o2h) * LSEQ + w * 1024;
    const uint32_t* gwp = fbp + ((size_t)b * 512 + o2g) * LSEQ + w * 1024;
    uint32_t* sw = sbuf[w];
    float* swf = (float*)sbuf[w];

    // ---- stage h+g windows (coalesced uint4) into swizzled LDS ----
#pragma unroll
    for (int i = 0; i < 4; ++i) {
        uint4 v = *(const uint4*)(hwp + i * 256 + lane * 4);
        const uint32_t g = i * 64 + lane;
        const uint32_t gs = g ^ ((g >> 3) & 7);
        *(uint4*)&sw[gs * 4] = v;
    }
#pragma unroll
    for (int i = 0; i < 4; ++i) {
        uint4 v = *(const uint4*)(gwp + i * 256 + lane * 4);
        const uint32_t g = i * 64 + lane;
        const uint32_t gs = g ^ ((g >> 3) & 7);
        *(uint4*)&sw[1024 + gs * 4] = v;
    }
    asm volatile("s_waitcnt lgkmcnt(0)" ::: "memory");

    // ---- per-thread chunk: 16 l, 2 channels ----
    float av0[16], vv0[16], av1[16], vv1[16];
#pragma unroll
    for (int q = 0; q < 4; ++q) {
        const uint32_t g = lane * 4 + q;
        const uint32_t gs = g ^ ((g >> 3) & 7);
        uint4 hw4 = *(const uint4*)&sw[gs * 4];
        uint4 gw4 = *(const uint4*)&sw[1024 + gs * 4];
        const uint32_t hws[4] = {hw4.x, hw4.y, hw4.z, hw4.w};
        const uint32_t gws[4] = {gw4.x, gw4.y, gw4.z, gw4.w};
#pragma unroll
        for (int s = 0; s < 4; ++s) {
            const int mo = q * 4 + s;
            {
                float g_ = fminf(fmaxf(bf16_lo(gws[s]), -30.f), 30.f);
                float eg = __expf(g_);
                float a  = rsqrtf(fmaf(eg, eg, 1.f));
                float h_ = bf16_lo(hws[s]);
                av0[mo] = a;
                vv0[mo] = a * eg * copysignf(fmaxf(fabsf(h_), 1e-6f), h_);
            }
            {
                float g_ = fminf(fmaxf(bf16_hi(gws[s]), -30.f), 30.f);
                float eg = __expf(g_);
                float a  = rsqrtf(fmaf(eg, eg, 1.f));
                float h_ = bf16_hi(hws[s]);
                av1[mo] = a;
                vv1[mo] = a * eg * copysignf(fmaxf(fabsf(h_), 1e-6f), h_);
            }
        }
    }

    // ---- local composites (scan order) ----
    float A0 = 1.f, B0 = 0.f, A1 = 1.f, B1 = 0.f;
    if (dir == 0) {
#pragma unroll
        for (int i = 0; i < 16; ++i) {
            B0 = fmaf(av0[i], B0, vv0[i]); A0 *= av0[i];
            B1 = fmaf(av1[i], B1, vv1[i]); A1 *= av1[i];
        }
    } else {
#pragma unroll
        for (int i = 15; i >= 0; --i) {
            B0 = fmaf(av0[i], B0, vv0[i]); A0 *= av0[i];
            B1 = fmaf(av1[i], B1, vv1[i]); A1 *= av1[i];
        }
    }

    // ---- wave scan of affine composites ----
    if (dir == 0) {
#pragma unroll
        for (int off = 1; off < 64; off <<= 1) {
            float Ap0 = __shfl_up(A0, (unsigned)off, 64), Bp0 = __shfl_up(B0, (unsigned)off, 64);
            float Ap1 = __shfl_up(A1, (unsigned)off, 64), Bp1 = __shfl_up(B1, (unsigned)off, 64);
            if (lane >= off) {
                B0 = fmaf(A0, Bp0, B0); A0 *= Ap0;
                B1 = fmaf(A1, Bp1, B1); A1 *= Ap1;
            }
        }
        if (lane == 63) { sA0[w] = A0; sB0[w] = B0; sA1[w] = A1; sB1[w] = B1; }
    } else {
#pragma unroll
        for (int off = 1; off < 64; off <<= 1) {
            float Ap0 = __shfl_down(A0, (unsigned)off, 64), Bp0 = __shfl_down(B0, (unsigned)off, 64);
            float Ap1 = __shfl_down(A1, (unsigned)off, 64), Bp1 = __shfl_down(B1, (unsigned)off, 64);
            if (lane + off < 64) {
                B0 = fmaf(A0, Bp0, B0); A0 *= Ap0;
                B1 = fmaf(A1, Bp1, B1); A1 *= Ap1;
            }
        }
        if (lane == 0) { sA0[w] = A0; sB0[w] = B0; sA1[w] = A1; sB1[w] = B1; }
    }
    __syncthreads();
    float WB0 = 0.f, WB1 = 0.f;
    if (dir == 0) {
        for (int wv = 0; wv < w; ++wv) {
            WB0 = fmaf(sA0[wv], WB0, sB0[wv]);
            WB1 = fmaf(sA1[wv], WB1, sB1[wv]);
        }
    } else {
        for (int wv = 7; wv > w; --wv) {
            WB0 = fmaf(sA0[wv], WB0, sB0[wv]);
            WB1 = fmaf(sA1[wv], WB1, sB1[wv]);
        }
    }
    float eA0, eB0, eA1, eB1;
    if (dir == 0) {
        eA0 = __shfl_up(A0, 1u, 64); eB0 = __shfl_up(B0, 1u, 64);
        eA1 = __shfl_up(A1, 1u, 64); eB1 = __shfl_up(B1, 1u, 64);
        if (lane == 0) { eA0 = 1.f; eB0 = 0.f; eA1 = 1.f; eB1 = 0.f; }
    } else {
        eA0 = __shfl_down(A0, 1u, 64); eB0 = __shfl_down(B0, 1u, 64);
        eA1 = __shfl_down(A1, 1u, 64); eB1 = __shfl_down(B1, 1u, 64);
        if (lane == 63) { eA0 = 1.f; eB0 = 0.f; eA1 = 1.f; eB1 = 0.f; }
    }
    float H0 = fmaf(eA0, WB0, eB0);
    float H1 = fmaf(eA1, WB1, eB1);

    // ---- final serial pass (results into vv, memory order) ----
    if (dir == 0) {
#pragma unroll
        for (int i = 0; i < 16; ++i) {
            H0 = fmaf(av0[i], H0, vv0[i]); vv0[i] = H0;
            H1 = fmaf(av1[i], H1, vv1[i]); vv1[i] = H1;
        }
    } else {
#pragma unroll
        for (int i = 15; i >= 0; --i) {
            H0 = fmaf(av0[i], H0, vv0[i]); vv0[i] = H0;
            H1 = fmaf(av1[i], H1, vv1[i]); vv1[i] = H1;
        }
    }

    // ---- write back: stage per-channel fp32 into LDS, coalesced out stores --
#pragma unroll
    for (int q = 0; q < 4; ++q) {
        const uint32_t g = lane * 4 + q;
        const uint32_t gs = g ^ ((g >> 3) & 7);
        *(float4*)&swf[gs * 4] =
            make_float4(vv0[q * 4], vv0[q * 4 + 1], vv0[q * 4 + 2], vv0[q * 4 + 3]);
        *(float4*)&swf[1024 + gs * 4] =
            make_float4(vv1[q * 4], vv1[q * 4 + 1], vv1[q * 4 + 2], vv1[q * 4 + 3]);
    }
    asm volatile("s_waitcnt lgkmcnt(0)" ::: "memory");
    const int c0 = 2 * p, c1 = 2 * p + 1;
    float* orow0 = out + ((size_t)b * 512 + dir * 256 + c0) * LSEQ + w * 1024;
    float* orow1 = out + ((size_t)b * 512 + dir * 256 + c1) * LSEQ + w * 1024;
#pragma unroll
    for (int i = 0; i < 4; ++i) {
        const uint32_t g = i * 64 + lane;
        const uint32_t gs = g ^ ((g >> 3) & 7);
        *(float4*)(orow0 + i * 256 + lane * 4) = *(const float4*)&swf[gs * 4];
        *(float4*)(orow1 + i * 256 + lane * 4) = *(const float4*)&swf[1024 + gs * 4];
    }
}

// ---------------- launch ----------------
extern "C" void kernel_launch(void* const* d_in, const int* in_sizes, int n_in,
                              void* d_out, int out_size, void* d_ws, size_t ws_size,
                              hipStream_t stream) {
    const float* x = (const float*)d_in[0];  // (8, 512, 8192)
    const float* W = (const float*)d_in[1];  // (1024, 512, 1)
    float* out = (float*)d_out;              // (8, 512, 8192)

    uint32_t* Wnb = (uint32_t*)d_ws;                                  // 1 MB
    uint32_t* fbp = (uint32_t*)((char*)d_ws + (size_t)NO * DIN * 2);  // 134 MB

    norm_kernel<<<dim3(NO), dim3(64), 0, stream>>>(W, Wnb);
    gemm_kernel<<<dim3(512, NB), dim3(256), 0, stream>>>((const uint16_t*)Wnb, x, fbp);
    scan_kernel<<<dim3(256, NB), dim3(512), 0, stream>>>(fbp, out);
}